// Round 6
// baseline (99.186 us; speedup 1.0000x reference)
//
#include <hip/hip_runtime.h>

// GruDirection3d forward, d1=d2=d3=1. B=2, C=96, D=H=W=32.
// out[b,c,d,y,x] = z*h_tilde + (1-z)*out[b,c,d-1,y-1,x-1], border = h0.
//
// HELIX DECOMPOSITION (round-5, verified): thread (a,b) owns, at plane d,
// the voxel y=(a+d)&31, x=(b+d)&31. The diagonal predecessor is the same
// thread's previous voxel; a wrap (y==0 || x==0) is exactly the h0 border
// (chain reset). Register-resident recurrence: no LDS, no barriers, no
// cross-thread traffic. A wave's lanes cover whole 128-B rows (cyclically
// rotated) -> perfectly coalesced loads and stores. 768 blocks x 256
// threads = 3 blocks/CU on all 256 CUs.
//
// ROUND-6 CHANGE: full 32-plane register preload (64 back-to-back loads per
// thread) instead of a depth-8 ring. Round-5 post-mortem: the kernel ran at
// 2.7 TB/s with memory pipes idle (1 vmem instr per ~58 cy/CU) -> stall-
// bound, and the depth-8 ring pins in-flight bytes at ~49 KB/CU regardless
// of access width. Full preload puts ~196 KB/CU in flight (the whole read
// set chip-wide), so queueing-inflated HBM latency is covered ~20x over.
// The compiler inserts exact per-register vmcnt waits, so the d-sweep
// starts as soon as plane 0 lands. Loads/stores are nontemporal (inputs
// and outputs are touched exactly once -> skip L2 pollution).

#define DD 32

__global__ __launch_bounds__(256) void gru3d_helix_pl(
    const float* __restrict__ z,
    const float* __restrict__ ht,
    const float* __restrict__ h0p,
    float* __restrict__ out)
{
    const int blk  = blockIdx.x;         // 0..767 = slab*4 + agrp
    const int slab = blk >> 2;           // 0..191  (b*96 + c)
    const int agrp = blk & 3;            // which 8-row band of 'a'
    const int tid  = threadIdx.x;        // 0..255
    const int a    = (agrp << 3) + (tid >> 5);
    const int b    = tid & 31;

    const float h0 = h0p[0];

    const size_t base = (size_t)slab * (DD * 1024);
    const float* __restrict__ zb = z   + base;
    const float* __restrict__ tb = ht  + base;
    float*       __restrict__ ob = out + base;

    // Offset of this thread's voxel at plane d (pure bit-concat).
    auto off = [&](int d) -> int {
        return (d << 10) | (((a + d) & 31) << 5) | ((b + d) & 31);
    };

    // FULL preload: 64 nontemporal dword loads, all in flight at once.
    // Issue order z,t per ascending plane = consumption order, so the
    // vmcnt FIFO retires exactly as the sweep consumes.
    float zr[DD], tr[DD];
    #pragma unroll
    for (int d = 0; d < DD; ++d) {
        zr[d] = __builtin_nontemporal_load(zb + off(d));
        tr[d] = __builtin_nontemporal_load(tb + off(d));
    }

    float h = h0;                        // plane -1 "value": the border

    #pragma unroll
    for (int d = 0; d < DD; ++d) {
        // Border reset: voxel on the y==0 or x==0 face -> pred = h0.
        const bool border = (((a + d) & 31) == 0) | (((b + d) & 31) == 0);
        const float pred  = border ? h0 : h;

        h = zr[d] * (tr[d] - pred) + pred;        // z*ht + (1-z)*pred
        __builtin_nontemporal_store(h, ob + off(d));  // fire-and-forget
    }
}

extern "C" void kernel_launch(void* const* d_in, const int* in_sizes, int n_in,
                              void* d_out, int out_size, void* d_ws, size_t ws_size,
                              hipStream_t stream) {
    const float* z  = (const float*)d_in[0];
    const float* ht = (const float*)d_in[1];
    const float* h0 = (const float*)d_in[2];
    float* out      = (float*)d_out;

    const int BC = 2 * 96;               // 192 slabs, 4 blocks each
    gru3d_helix_pl<<<dim3(BC * 4), dim3(256), 0, stream>>>(z, ht, h0, out);
}

// Round 7
// 94.935 us; speedup vs baseline: 1.0448x; 1.0448x over previous
//
#include <hip/hip_runtime.h>

// GruDirection3d forward, d1=d2=d3=1. B=2, C=96, D=H=W=32.
// out[b,c,d,y,x] = z*h_tilde + (1-z)*out[b,c,d-1,y-1,x-1], border = h0.
//
// HELIX DECOMPOSITION, y-rotation only + float2 (round-7).
// Thread (a,bg) owns, at plane d, voxels y=(a+d)&31, x={2bg, 2bg+1} (x is
// FIXED per thread so vector loads never wrap; only y rotates). The
// diagonal predecessor (d-1, y-1, x-1) is then:
//   pred[x=2bg+1] = own previous h[x=2bg]          (register)
//   pred[x=2bg]   = lane (bg-1)'s previous h[2bg-1] (__shfl_up by 1)
// Borders: y wrap ((a+d)&31==0), x0==0 (bg==0), and d==0 -> pred = h0.
//
// Round-6 post-mortem: sync (r3), MLP depth (r6), occupancy+pattern (r5)
// all neutral; the one untested-in-this-structure property is REQUEST
// WIDTH — every helix used scalar dword (4B/lane). The 6.3 TB/s ceiling
// (m13) is a float4 copy; G13 sweet spot is 8-16B/lane. This version makes
// all global traffic dwordx2 (8B/lane, 512B/wave-instr). Round 4's float4
// test was confounded by 1-block/CU occupancy; here we keep full coverage:
// 768 blocks x 128 threads = 3 blocks/CU on all 256 CUs, 6 waves/CU,
// depth-8 float2 ring (~49 KB/CU in flight, 5x Little's-law need).
// Nontemporal hints reverted (r6 regression).

#define DD 32
#define PF 8                     // prefetch ring depth (planes)

__global__ __launch_bounds__(128) void gru3d_helix_f2(
    const float* __restrict__ z,
    const float* __restrict__ ht,
    const float* __restrict__ h0p,
    float* __restrict__ out)
{
    const int blk  = blockIdx.x;         // 0..767 = slab*4 + band
    const int slab = blk >> 2;           // 0..191  (b*96 + c)
    const int band = blk & 3;            // which 8-row band of 'a'
    const int tid  = threadIdx.x;        // 0..127 = a_local*16 + bg
    const int a    = (band << 3) + (tid >> 4);
    const int bg   = tid & 15;           // x-group: x = 2bg, 2bg+1

    const float h0 = h0p[0];

    const size_t base = (size_t)slab * (DD * 1024);
    const float* __restrict__ zb = z   + base;
    const float* __restrict__ tb = ht  + base;
    float*       __restrict__ ob = out + base;

    // Offset of this thread's float2 at plane d (8B-aligned, never wraps).
    auto off = [&](int d) -> int {
        return (d << 10) | (((a + d) & 31) << 5) | (bg << 1);
    };

    // Prologue: fill the ring with planes 0..PF-1 (dwordx2 loads).
    float2 zr[PF], tr[PF];
    #pragma unroll
    for (int p = 0; p < PF; ++p) {
        zr[p] = *reinterpret_cast<const float2*>(zb + off(p));
        tr[p] = *reinterpret_cast<const float2*>(tb + off(p));
    }

    float hx = h0, hy = h0;              // this thread's previous-plane h

    #pragma unroll
    for (int d = 0; d < DD; ++d) {
        const int s = d & (PF - 1);

        // Neighbor's previous h[2bg-1] (lane bg-1 within the same row).
        const float n = __shfl_up(hy, 1);

        float px = (bg == 0) ? h0 : n;   // x==0 face -> border
        float py = hx;
        const bool yb = (d == 0) | (((a + d) & 31) == 0);  // d==0 or y wrap
        if (yb) { px = h0; py = h0; }

        hx = zr[s].x * (tr[s].x - px) + px;   // z*ht + (1-z)*pred
        hy = zr[s].y * (tr[s].y - py) + py;

        *reinterpret_cast<float2*>(ob + off(d)) = make_float2(hx, hy);

        if (d + PF < DD) {               // refill ring
            zr[s] = *reinterpret_cast<const float2*>(zb + off(d + PF));
            tr[s] = *reinterpret_cast<const float2*>(tb + off(d + PF));
        }
    }
}

extern "C" void kernel_launch(void* const* d_in, const int* in_sizes, int n_in,
                              void* d_out, int out_size, void* d_ws, size_t ws_size,
                              hipStream_t stream) {
    const float* z  = (const float*)d_in[0];
    const float* ht = (const float*)d_in[1];
    const float* h0 = (const float*)d_in[2];
    float* out      = (float*)d_out;

    const int BC = 2 * 96;               // 192 slabs, 4 bands each
    gru3d_helix_f2<<<dim3(BC * 4), dim3(128), 0, stream>>>(z, ht, h0, out);
}

// Round 8
// 93.448 us; speedup vs baseline: 1.0614x; 1.0159x over previous
//
#include <hip/hip_runtime.h>

// GruDirection3d forward, d1=d2=d3=1. B=2, C=96, D=H=W=32.
// out[b,c,d,y,x] = z*h_tilde + (1-z)*out[b,c,d-1,y-1,x-1], border = h0.
//
// HELIX DECOMPOSITION (r5 geometry, verified): thread (a,b) owns, at plane
// d, the voxel y=(a+d)&31, x=(b+d)&31. The diagonal predecessor is the same
// thread's previous voxel; a wrap (y==0 || x==0) is exactly the h0 border.
// Register-resident recurrence: no LDS, no barriers, no cross-thread
// traffic. A wave's lanes cover whole 128-B rows (cyclically rotated) ->
// perfectly coalesced scalar-dword streams. 768 blocks x 256 threads =
// 3 blocks/CU on all 256 CUs, 3 waves/SIMD (max TLP this problem supplies).
//
// ROUND-8 CHANGE: pin the prefetch schedule with sched_barrier(0).
// Round-1 (the only round where the gru dispatch's counters were directly
// visible) showed VGPR_Count = 12 — the compiler had COLLAPSED the source-
// level prefetch ring and sunk loads to just-before-use (~2 in flight per
// thread, ~6 KB/CU). Little's law at queue-inflated HBM latency then gives
// exactly the ~2.7 TB/s observed in every round, explaining why all five
// structural experiments (barriers, preload, width, occupancy) were
// neutral: the scheduler re-sank the loads identically each time.
// The whole unrolled body is one basic block, so the MachineScheduler is
// the only reorderer; a sched_barrier(0) at the end of each step fences it:
// refill loads issued at step d can no longer sink to their use at d+PF.
// Correctness (vmcnt waits) remains fully compiler-managed.

#define DD 32
#define PF 12                   // ring depth: 24 outstanding loads/thread

__global__ __launch_bounds__(256) void gru3d_helix_pin(
    const float* __restrict__ z,
    const float* __restrict__ ht,
    const float* __restrict__ h0p,
    float* __restrict__ out)
{
    const int blk  = blockIdx.x;         // 0..767 = slab*4 + agrp
    const int slab = blk >> 2;           // 0..191  (b*96 + c)
    const int agrp = blk & 3;            // which 8-row band of 'a'
    const int tid  = threadIdx.x;        // 0..255
    const int a    = (agrp << 3) + (tid >> 5);
    const int b    = tid & 31;

    const float h0 = h0p[0];

    const size_t base = (size_t)slab * (DD * 1024);
    const float* __restrict__ zb = z   + base;
    const float* __restrict__ tb = ht  + base;
    float*       __restrict__ ob = out + base;

    // Offset of this thread's voxel at plane d (pure bit-concat).
    auto off = [&](int d) -> int {
        return (d << 10) | (((a + d) & 31) << 5) | ((b + d) & 31);
    };

    // Prologue: fill the ring with planes 0..PF-1, then FENCE so these 24
    // loads cannot be sunk into the sweep by the scheduler.
    float zr[PF], tr[PF];
    #pragma unroll
    for (int p = 0; p < PF; ++p) {
        zr[p] = zb[off(p)];
        tr[p] = tb[off(p)];
    }
    __builtin_amdgcn_sched_barrier(0);

    float h = h0;                        // plane -1 "value": the border

    #pragma unroll
    for (int d = 0; d < DD; ++d) {
        const int s = d % PF;            // compile-time under full unroll

        // Border reset: voxel on the y==0 or x==0 face -> pred = h0.
        const bool border = (((a + d) & 31) == 0) | (((b + d) & 31) == 0);
        const float pred  = border ? h0 : h;

        h = zr[s] * (tr[s] - pred) + pred;   // z*ht + (1-z)*pred
        ob[off(d)] = h;                      // fire-and-forget store

        if (d + PF < DD) {                   // refill ring, PF planes ahead
            zr[s] = zb[off(d + PF)];
            tr[s] = tb[off(d + PF)];
        }
        // Fence: this step's refill loads stay HERE (PF steps before use);
        // nothing from later steps may be hoisted above, nothing from this
        // step may sink below.
        __builtin_amdgcn_sched_barrier(0);
    }
}

extern "C" void kernel_launch(void* const* d_in, const int* in_sizes, int n_in,
                              void* d_out, int out_size, void* d_ws, size_t ws_size,
                              hipStream_t stream) {
    const float* z  = (const float*)d_in[0];
    const float* ht = (const float*)d_in[1];
    const float* h0 = (const float*)d_in[2];
    float* out      = (float*)d_out;

    const int BC = 2 * 96;               // 192 slabs, 4 bands each
    gru3d_helix_pin<<<dim3(BC * 4), dim3(256), 0, stream>>>(z, ht, h0, out);
}

// Round 9
// 92.489 us; speedup vs baseline: 1.0724x; 1.0104x over previous
//
#include <hip/hip_runtime.h>

// GruDirection3d forward, d1=d2=d3=1. B=2, C=96, D=H=W=32.
// out[b,c,d,y,x] = z*h_tilde + (1-z)*out[b,c,d-1,y-1,x-1], border = h0.
//
// HELIX + SEGMENTED PARALLEL SCAN (round-9).
//
// Helix (r5, verified): chain (a,b) visits voxel y=(a+d)&31, x=(b+d)&31 at
// plane d; a face wrap (y==0||x==0) resets the chain to the h0 border.
//
// r2-r8 post-mortem: every structural lever (barriers, pattern, width, ring
// depth, schedule pinning) was neutral at ~2.7 TB/s because walking each
// chain serially caps the kernel at 196k threads = 12 waves/CU; HBM
// in-flight bytes are supplied by WAVE COUNT on this chip, and 12 waves/CU
// sustains ~2.7 TB/s vs 6.3+ TB/s for 32-waves/CU streaming kernels (the
// harness fills in the same capture).
//
// Fix: the recurrence is linear, h = A*h_prev + B with A=(1-z), B=z*ht;
// border voxels absorb the reset as A'=0, B'=z*ht+(1-z)*h0 (A'=0 kills the
// upstream dependence -> segmented scan falls out of plain composition).
// Each 32-chain splits into NSEG=4 segments of SEGL=8 planes:
//   pass 1: each thread composes its segment transform (8 serial fma-ish),
//   LDS:    exclusive prefix over the 4 segment transforms (2 KB, 1 barrier),
//   pass 2: replay the 8 planes from register-held z,ht; store.
// Traffic unchanged (each voxel loaded/stored exactly once); thread count
// x4 = 786k threads = 32 waves/CU = full residency. Lanes vary b fastest ->
// dense rotated 128-B rows, fully coalesced loads and stores.

#define DD   32
#define SEGL 8                  // planes per segment
#define NSEG 4                  // segments per chain

__global__ __launch_bounds__(256) void gru3d_scan(
    const float* __restrict__ z,
    const float* __restrict__ ht,
    const float* __restrict__ h0p,
    float* __restrict__ out)
{
    __shared__ float sA[256];
    __shared__ float sB[256];

    const int blk   = blockIdx.x;        // 0..3071 = slab*16 + band
    const int slab  = blk >> 4;          // 0..191  (b*96 + c)
    const int band  = blk & 15;          // 16 bands of 2 'a' rows
    const int tid   = threadIdx.x;       // a_loc*128 + seg*32 + b
    const int a_loc = tid >> 7;
    const int seg   = (tid >> 5) & 3;
    const int b     = tid & 31;
    const int a     = (band << 1) | a_loc;
    const int d0    = seg << 3;          // first plane of this segment

    const float h0 = h0p[0];

    const size_t base = (size_t)slab * (DD * 1024);
    const float* __restrict__ zb = z   + base;
    const float* __restrict__ tb = ht  + base;
    float*       __restrict__ ob = out + base;

    // Offset of chain (a,b)'s voxel at plane d (pure bit-concat).
    auto off = [&](int d) -> int {
        return (d << 10) | (((a + d) & 31) << 5) | ((b + d) & 31);
    };

    // Load this segment's 16 inputs up front (independent, kept in VGPRs —
    // both passes consume them). Fence so the batch isn't sunk.
    float zv[SEGL], tv[SEGL];
    #pragma unroll
    for (int k = 0; k < SEGL; ++k) {
        zv[k] = zb[off(d0 + k)];
        tv[k] = tb[off(d0 + k)];
    }
    __builtin_amdgcn_sched_barrier(0);

    // Pass 1: compose the segment transform T = (Aa, Ba).
    float Aa = 1.0f, Ba = 0.0f;
    #pragma unroll
    for (int k = 0; k < SEGL; ++k) {
        const int d = d0 + k;
        const bool border = (((a + d) & 31) == 0) | (((b + d) & 31) == 0);
        const float omz = 1.0f - zv[k];
        const float Ad  = border ? 0.0f : omz;
        float       Bd  = zv[k] * tv[k];
        if (border) Bd = fmaf(omz, h0, Bd);   // z*ht + (1-z)*h0
        Aa = Ad * Aa;                          // T_d ∘ T_acc
        Ba = fmaf(Ad, Ba, Bd);
    }
    sA[tid] = Aa;
    sB[tid] = Ba;
    __syncthreads();

    // Exclusive prefix over the NSEG segment transforms of this chain
    // (ascending j, same compose update; <=3 iterations, conflict-free:
    // lanes read consecutive LDS words).
    float Ap = 1.0f, Bp = 0.0f;
    for (int j = 0; j < seg; ++j) {
        const int t = (a_loc << 7) | (j << 5) | b;
        const float Aj = sA[t];
        const float Bj = sB[t];
        Ap = Aj * Ap;
        Bp = fmaf(Aj, Bp, Bj);
    }
    // Chain state entering this segment (seg 0: identity -> h0).
    float h = fmaf(Ap, h0, Bp);

    // Pass 2: replay the 8 planes and store (fire-and-forget).
    #pragma unroll
    for (int k = 0; k < SEGL; ++k) {
        const int d = d0 + k;
        const bool border = (((a + d) & 31) == 0) | (((b + d) & 31) == 0);
        const float pred  = border ? h0 : h;
        h = fmaf(zv[k], tv[k] - pred, pred);   // z*ht + (1-z)*pred
        ob[off(d)] = h;
    }
}

extern "C" void kernel_launch(void* const* d_in, const int* in_sizes, int n_in,
                              void* d_out, int out_size, void* d_ws, size_t ws_size,
                              hipStream_t stream) {
    const float* z  = (const float*)d_in[0];
    const float* ht = (const float*)d_in[1];
    const float* h0 = (const float*)d_in[2];
    float* out      = (float*)d_out;

    const int BC = 2 * 96;               // 192 slabs, 16 blocks each
    gru3d_scan<<<dim3(BC * 16), dim3(256), 0, stream>>>(z, ht, h0, out);
}